// Round 2
// baseline (624.474 us; speedup 1.0000x reference)
//
#include <hip/hip_runtime.h>

// ---------------- constants ----------------
#define NTOK 65536
#define DIN  1024
#define H    512
#define HH   256
#define NREG 16
#define MPR  4096   // patches per region = NTOK/NREG

// ---------------- helpers ----------------
__device__ __forceinline__ unsigned short f2bf(float f) {
  unsigned u = __float_as_uint(f);
  u += 0x7fffu + ((u >> 16) & 1u);   // RNE
  return (unsigned short)(u >> 16);
}
__device__ __forceinline__ float bf2f(unsigned short s) {
  return __uint_as_float(((unsigned)s) << 16);
}
__device__ __forceinline__ float gelu_exact(float x) {
  return 0.5f * x * (1.0f + erff(x * 0.70710678118654752440f));
}
// packed fp32x2 -> bf16x2 (hardware RNE convert, 1 instr)
__device__ __forceinline__ unsigned cvt_pk_bf16(float lo, float hi) {
  unsigned r;
  asm("v_cvt_pk_bf16_f32 %0, %1, %2" : "=v"(r) : "v"(lo), "v"(hi));
  return r;
}
__device__ __forceinline__ unsigned short f2bf_hw(float f) {
  unsigned r;
  asm("v_cvt_pk_bf16_f32 %0, %1, %2" : "=v"(r) : "v"(f), "v"(f));
  return (unsigned short)r;
}
// fast tanh: 1 - 2/(exp(2x)+1); monotone, saturates to ±1, no NaN at |x|→inf
__device__ __forceinline__ float fast_tanh(float x) {
  float e = __expf(2.0f * x);
  return 1.0f - 2.0f * __builtin_amdgcn_rcpf(e + 1.0f);
}

typedef __attribute__((ext_vector_type(8))) short shortx8;       // 8 bf16 (4 VGPRs)
typedef __attribute__((ext_vector_type(4))) float floatx4;       // 4 fp32
typedef __attribute__((ext_vector_type(4))) unsigned int uintx4; // 16B store

__device__ __forceinline__ void gl_lds16(const void* g, void* l) {
  __builtin_amdgcn_global_load_lds(
      (const __attribute__((address_space(1))) void*)g,
      (__attribute__((address_space(3))) void*)l, 16, 0, 0);
}

// chunk-XOR swizzle: 16B chunk for (row, seg) lives at linear slot row*4 + (seg^((row>>1)&3)).
// Verified last round: SQ_LDS_BANK_CONFLICT dropped to 0.
__device__ __forceinline__ int swz8(int row, int seg) {
  return (row * 4 + (seg ^ ((row >> 1) & 3))) * 8;  // short index of chunk start
}

// ---------------- K0: weight transpose + bf16 convert ----------------
__global__ __launch_bounds__(256) void k0_prep(const float* __restrict__ W1,
                                               const float* __restrict__ Wa1,
                                               unsigned short* __restrict__ W1t,
                                               unsigned short* __restrict__ Wa1t) {
  int idx = blockIdx.x * 256 + threadIdx.x;
  if (idx < DIN * H) {                 // 524288
    int n = idx >> 10, k = idx & 1023; // W1t[n][k] = W1[k][n]
    W1t[idx] = f2bf(W1[k * H + n]);
  } else {
    int i2 = idx - DIN * H;            // < 131072
    int n = i2 >> 9, k = i2 & 511;     // Wa1t[n][k] = Wa1[k][n]
    Wa1t[i2] = f2bf(Wa1[k * HH + n]);
  }
}

// ---------------- K1: Eb = GELU(X @ W1 + b1), bf16 out ----------------
// M=65536, K=1024, N=512(full). BM=128, BN=512, BK=32. grid(512), 512 thr (8 waves 2x4).
// 2-phase double-buffered pipeline (T3 minimum recipe): STAGE(t+1) issued BEFORE
// ds_read+MFMA of tile t; single vmcnt-drain+barrier per K-step at the END, so the
// prefetch has the whole compute phase to land.
__global__ __launch_bounds__(512) void k1_gemm1(const float* __restrict__ X,
                                                const unsigned short* __restrict__ W1t,
                                                const float* __restrict__ b1,
                                                unsigned short* __restrict__ Eb) {
  __shared__ __align__(16) short lA[2][128 * 32];  // 2 x 8 KB
  __shared__ __align__(16) short lB[2][512 * 32];  // 2 x 32 KB
  const int tid = threadIdx.x;
  const int rowBase = blockIdx.x * 128;
  const int lane = tid & 63;
  const int wave = tid >> 6;                // 0..7
  const int wr = wave >> 2, wc = wave & 3;  // 2x4 waves: each wave 64 rows x 128 cols
  const int l15 = lane & 15, quad = lane >> 4;

  floatx4 acc[4][8] = {};

  // A staging: thread owns chunk (row = tid>>2, seg = tid&3) = 8 fp32 -> 8 bf16 (16B)
  const int arow = tid >> 2, aseg = tid & 3;
  const float* aSrc = X + (size_t)(rowBase + arow) * DIN + aseg * 8;
  const int aOff = swz8(arow, aseg);

  // ---- prologue: stage tile 0 into buffer 0
#pragma unroll
  for (int s = 0; s < 4; s++) {
    int c = tid + s * 512;
    int n = c >> 2;
    int seg = (c & 3) ^ ((n >> 1) & 3);
    gl_lds16(W1t + (size_t)n * DIN + seg * 8, &lB[0][c * 8]);
  }
  {
    const floatx4* src = (const floatx4*)aSrc;
    floatx4 f0 = src[0], f1 = src[1];
    uintx4 u;
    u[0] = cvt_pk_bf16(f0[0], f0[1]);
    u[1] = cvt_pk_bf16(f0[2], f0[3]);
    u[2] = cvt_pk_bf16(f1[0], f1[1]);
    u[3] = cvt_pk_bf16(f1[2], f1[3]);
    *(uintx4*)(&lA[0][aOff]) = u;
  }
  __syncthreads();

#pragma unroll 1
  for (int t = 0; t < 32; ++t) {
    const int cur = t & 1, nxt = cur ^ 1;
    floatx4 f0, f1;
    // --- issue next-tile staging first (loads fly under the MFMAs)
    if (t < 31) {
      const int kb = (t + 1) * 32;
#pragma unroll
      for (int s = 0; s < 4; s++) {
        int c = tid + s * 512;
        int n = c >> 2;
        int seg = (c & 3) ^ ((n >> 1) & 3);
        gl_lds16(W1t + (size_t)n * DIN + kb + seg * 8, &lB[nxt][c * 8]);
      }
      const floatx4* src = (const floatx4*)(aSrc + kb);
      f0 = src[0];
      f1 = src[1];
    }
    // --- fragments from current buffer + MFMA
    shortx8 aF[4], bF[8];
#pragma unroll
    for (int i = 0; i < 4; i++)
      aF[i] = *(const shortx8*)(&lA[cur][swz8(wr * 64 + i * 16 + l15, quad)]);
#pragma unroll
    for (int j = 0; j < 8; j++)
      bF[j] = *(const shortx8*)(&lB[cur][swz8(wc * 128 + j * 16 + l15, quad)]);
#pragma unroll
    for (int i = 0; i < 4; i++)
#pragma unroll
      for (int j = 0; j < 8; j++)
        acc[i][j] = __builtin_amdgcn_mfma_f32_16x16x32_bf16(aF[i], bF[j], acc[i][j], 0, 0, 0);
    // --- write-late: convert A regs and place into next buffer, then barrier
    if (t < 31) {
      uintx4 u;
      u[0] = cvt_pk_bf16(f0[0], f0[1]);
      u[1] = cvt_pk_bf16(f0[2], f0[3]);
      u[2] = cvt_pk_bf16(f1[0], f1[1]);
      u[3] = cvt_pk_bf16(f1[2], f1[3]);
      *(uintx4*)(&lA[nxt][aOff]) = u;
      __syncthreads();  // drains vmcnt (gl_lds of nxt) + lgkm (ds_write of nxt)
    }
  }

  // --- epilogue: bias + exact GELU + bf16 store
  const int row0 = rowBase + wr * 64;
#pragma unroll
  for (int j = 0; j < 8; j++) {
    int col = wc * 128 + j * 16 + l15;
    float bias = b1[col];
#pragma unroll
    for (int i = 0; i < 4; i++) {
      int rb = row0 + i * 16 + quad * 4;
#pragma unroll
      for (int v = 0; v < 4; v++) {
        float x = acc[i][j][v] + bias;
        Eb[(size_t)(rb + v) * H + col] = f2bf_hw(gelu_exact(x));
      }
    }
  }
}

// ---------------- K2: scores = tanh(Eb @ Wa1 + ba1) . Wa2  (fused, full-N) ----------------
// M=65536, K=512, N=256(full). BM=128, BN=256, BK=32. grid(512), 512 thr (8 waves 2x4).
// Double-buffered like k1; cross-wave LDS reduce writes scores directly (no atomics).
__global__ __launch_bounds__(512) void k2_gemm2(const unsigned short* __restrict__ Eb,
                                                const unsigned short* __restrict__ Wa1t,
                                                const float* __restrict__ ba1,
                                                const float* __restrict__ Wa2,
                                                float* __restrict__ scores) {
  __shared__ __align__(16) short lA[2][128 * 32];  // 2 x 8 KB
  __shared__ __align__(16) short lB[2][256 * 32];  // 2 x 16 KB
  __shared__ float part[4][128];
  const int tid = threadIdx.x;
  const int rowBase = blockIdx.x * 128;
  const int lane = tid & 63;
  const int wave = tid >> 6;
  const int wr = wave >> 2, wc = wave & 3;  // each wave: 64 rows x 64 cols
  const int l15 = lane & 15, quad = lane >> 4;

  floatx4 acc[4][4] = {};

  // ---- prologue: stage tile 0 into buffer 0
  {
    int c = tid;  // A: 512 chunks, 1/thread
    int n = c >> 2;
    int seg = (c & 3) ^ ((n >> 1) & 3);
    gl_lds16(Eb + (size_t)(rowBase + n) * H + seg * 8, &lA[0][c * 8]);
  }
#pragma unroll
  for (int s = 0; s < 2; s++) {  // B: 1024 chunks, 2/thread
    int c = tid + s * 512;
    int n = c >> 2;
    int seg = (c & 3) ^ ((n >> 1) & 3);
    gl_lds16(Wa1t + (size_t)n * H + seg * 8, &lB[0][c * 8]);
  }
  __syncthreads();

#pragma unroll 1
  for (int t = 0; t < 16; ++t) {
    const int cur = t & 1, nxt = cur ^ 1;
    if (t < 15) {
      const int kb = (t + 1) * 32;
      {
        int c = tid;
        int n = c >> 2;
        int seg = (c & 3) ^ ((n >> 1) & 3);
        gl_lds16(Eb + (size_t)(rowBase + n) * H + kb + seg * 8, &lA[nxt][c * 8]);
      }
#pragma unroll
      for (int s = 0; s < 2; s++) {
        int c = tid + s * 512;
        int n = c >> 2;
        int seg = (c & 3) ^ ((n >> 1) & 3);
        gl_lds16(Wa1t + (size_t)n * H + kb + seg * 8, &lB[nxt][c * 8]);
      }
    }
    shortx8 aF[4], bF[4];
#pragma unroll
    for (int i = 0; i < 4; i++)
      aF[i] = *(const shortx8*)(&lA[cur][swz8(wr * 64 + i * 16 + l15, quad)]);
#pragma unroll
    for (int j = 0; j < 4; j++)
      bF[j] = *(const shortx8*)(&lB[cur][swz8(wc * 64 + j * 16 + l15, quad)]);
#pragma unroll
    for (int i = 0; i < 4; i++)
#pragma unroll
      for (int j = 0; j < 4; j++)
        acc[i][j] = __builtin_amdgcn_mfma_f32_16x16x32_bf16(aF[i], bF[j], acc[i][j], 0, 0, 0);
    if (t < 15) __syncthreads();
  }

  // epilogue: p[i][v] = sum over this wave's 64 cols of tanh(acc + ba1) * Wa2
  float p[4][4];
#pragma unroll
  for (int i = 0; i < 4; i++)
#pragma unroll
    for (int v = 0; v < 4; v++) p[i][v] = 0.0f;
#pragma unroll
  for (int j = 0; j < 4; j++) {
    int col = wc * 64 + j * 16 + l15;
    float bias = ba1[col];
    float wa2 = Wa2[col];
#pragma unroll
    for (int i = 0; i < 4; i++)
#pragma unroll
      for (int v = 0; v < 4; v++)
        p[i][v] += fast_tanh(acc[i][j][v] + bias) * wa2;
  }
#pragma unroll
  for (int i = 0; i < 4; i++)
#pragma unroll
    for (int v = 0; v < 4; v++) {
      float t = p[i][v];
      t += __shfl_xor(t, 1, 16);
      t += __shfl_xor(t, 2, 16);
      t += __shfl_xor(t, 4, 16);
      t += __shfl_xor(t, 8, 16);
      p[i][v] = t;
    }
  if (l15 == 0) {
#pragma unroll
    for (int i = 0; i < 4; i++)
#pragma unroll
      for (int v = 0; v < 4; v++)
        part[wc][wr * 64 + i * 16 + quad * 4 + v] = p[i][v];
  }
  __syncthreads();
  if (tid < 128)
    scores[rowBase + tid] = part[0][tid] + part[1][tid] + part[2][tid] + part[3][tid];
}

// ---------------- K3a: per-region softmax weights ----------------
__global__ __launch_bounds__(256) void k3a_softmax(const float* __restrict__ scores,
                                                   float* __restrict__ wts) {
  const int r = blockIdx.x, tid = threadIdx.x;
  __shared__ float red[256];
  float m = -1e30f;
  for (int j = tid; j < MPR; j += 256) m = fmaxf(m, scores[r + NREG * j]);
  red[tid] = m;
  __syncthreads();
  for (int s = 128; s > 0; s >>= 1) {
    if (tid < s) red[tid] = fmaxf(red[tid], red[tid + s]);
    __syncthreads();
  }
  float mx = red[0];
  __syncthreads();
  float sum = 0.0f;
  for (int j = tid; j < MPR; j += 256) sum += expf(scores[r + NREG * j] - mx);
  red[tid] = sum;
  __syncthreads();
  for (int s = 128; s > 0; s >>= 1) {
    if (tid < s) red[tid] += red[tid + s];
    __syncthreads();
  }
  float inv = 1.0f / red[0];
  for (int j = tid; j < MPR; j += 256)
    wts[r + NREG * j] = expf(scores[r + NREG * j] - mx) * inv;
}

// ---------------- K3b: region_features[r][h] = sum_m w * Eb ----------------
__global__ __launch_bounds__(256) void k3b_wsum(const unsigned short* __restrict__ Eb,
                                                const float* __restrict__ wts,
                                                float* __restrict__ rf) {
  const int r = blockIdx.y;
  const int mc = blockIdx.x;
  const int tid = threadIdx.x;
  float a0 = 0.0f, a1 = 0.0f;
  for (int j = mc * 128; j < mc * 128 + 128; j++) {
    int n = r + NREG * j;
    float w = wts[n];
    unsigned v = *(const unsigned*)(Eb + (size_t)n * H + tid * 2);
    a0 += w * bf2f((unsigned short)(v & 0xffffu));
    a1 += w * bf2f((unsigned short)(v >> 16));
  }
  atomicAdd(&rf[r * H + tid * 2], a0);
  atomicAdd(&rf[r * H + tid * 2 + 1], a1);
}

// ---------------- K4a: slide_emb = GELU(rf @ Ws + bs) ----------------
__global__ __launch_bounds__(256) void k4a_slide(const float* __restrict__ rf,
                                                 const float* __restrict__ Ws,
                                                 const float* __restrict__ bs,
                                                 float* __restrict__ se) {
  const int r = blockIdx.x, tid = threadIdx.x;
  __shared__ float lrf[H];
  lrf[tid] = rf[r * H + tid];
  lrf[tid + 256] = rf[r * H + tid + 256];
  __syncthreads();
  float a0 = 0.0f, a1 = 0.0f;
  for (int k = 0; k < H; k++) {
    float x = lrf[k];
    a0 += x * Ws[k * H + tid];
    a1 += x * Ws[k * H + tid + 256];
  }
  se[r * H + tid] = gelu_exact(a0 + bs[tid]);
  se[r * H + tid + 256] = gelu_exact(a1 + bs[tid + 256]);
}

// ---------------- K4b: sscore[r] = tanh(se @ Wsa1 + bsa1) . Wsa2 + bsa2 ----------------
__global__ __launch_bounds__(256) void k4b_sscore(const float* __restrict__ se,
                                                  const float* __restrict__ Wsa1,
                                                  const float* __restrict__ bsa1,
                                                  const float* __restrict__ Wsa2,
                                                  const float* __restrict__ bsa2,
                                                  float* __restrict__ ss) {
  const int r = blockIdx.x, tid = threadIdx.x;
  __shared__ float lse[H];
  __shared__ float red[256];
  lse[tid] = se[r * H + tid];
  lse[tid + 256] = se[r * H + tid + 256];
  __syncthreads();
  float a = 0.0f;
  for (int k = 0; k < H; k++) a += lse[k] * Wsa1[k * HH + tid];
  red[tid] = tanhf(a + bsa1[tid]) * Wsa2[tid];
  __syncthreads();
  for (int s = 128; s > 0; s >>= 1) {
    if (tid < s) red[tid] += red[tid + s];
    __syncthreads();
  }
  if (tid == 0) ss[r] = red[0] + bsa2[0];
}

// ---------------- K4c: softmax over regions + classifier ----------------
__global__ __launch_bounds__(256) void k4c_final(const float* __restrict__ se,
                                                 const float* __restrict__ ss,
                                                 const float* __restrict__ Wc1,
                                                 const float* __restrict__ bc1,
                                                 const float* __restrict__ Wc2,
                                                 const float* __restrict__ bc2,
                                                 float* __restrict__ out) {
  const int tid = threadIdx.x;
  __shared__ float srep[H];
  __shared__ float r0[256], r1[256];
  float mx = -1e30f;
  for (int i = 0; i < NREG; i++) mx = fmaxf(mx, ss[i]);
  float wv[NREG];
  float den = 0.0f;
  for (int i = 0; i < NREG; i++) { wv[i] = expf(ss[i] - mx); den += wv[i]; }
  float inv = 1.0f / den;
  float s0 = 0.0f, s1 = 0.0f;
  for (int i = 0; i < NREG; i++) {
    float w = wv[i] * inv;
    s0 += w * se[i * H + tid];
    s1 += w * se[i * H + tid + 256];
  }
  srep[tid] = s0;
  srep[tid + 256] = s1;
  __syncthreads();
  float a = 0.0f;
  for (int k = 0; k < H; k++) a += srep[k] * Wc1[k * HH + tid];
  float g = gelu_exact(a + bc1[tid]);
  r0[tid] = g * Wc2[tid * 2];
  r1[tid] = g * Wc2[tid * 2 + 1];
  __syncthreads();
  for (int s = 128; s > 0; s >>= 1) {
    if (tid < s) { r0[tid] += r0[tid + s]; r1[tid] += r1[tid + s]; }
    __syncthreads();
  }
  if (tid == 0) {
    out[0] = r0[0] + bc2[0];
    out[1] = r1[0] + bc2[1];
  }
}

// ---------------- launcher ----------------
extern "C" void kernel_launch(void* const* d_in, const int* in_sizes, int n_in,
                              void* d_out, int out_size, void* d_ws, size_t ws_size,
                              hipStream_t stream) {
  const float* X    = (const float*)d_in[0];
  const float* W1   = (const float*)d_in[1];
  const float* b1   = (const float*)d_in[2];
  const float* Wa1  = (const float*)d_in[3];
  const float* ba1  = (const float*)d_in[4];
  const float* Wa2  = (const float*)d_in[5];
  // d_in[6] = ba2: constant shift inside softmax -> no effect, unused
  const float* Ws   = (const float*)d_in[7];
  const float* bs   = (const float*)d_in[8];
  const float* Wsa1 = (const float*)d_in[9];
  const float* bsa1 = (const float*)d_in[10];
  const float* Wsa2 = (const float*)d_in[11];
  const float* bsa2 = (const float*)d_in[12];
  const float* Wc1  = (const float*)d_in[13];
  const float* bc1  = (const float*)d_in[14];
  const float* Wc2  = (const float*)d_in[15];
  const float* bc2  = (const float*)d_in[16];
  float* out = (float*)d_out;

  char* ws = (char*)d_ws;
  constexpr size_t OFF_W1T  = 0;                                    // 1 MiB
  constexpr size_t OFF_WA1T = OFF_W1T + (size_t)H * DIN * 2;        // +256 KiB
  constexpr size_t OFF_EB   = OFF_WA1T + (size_t)HH * H * 2;        // +64 MiB
  constexpr size_t OFF_SC   = OFF_EB + (size_t)NTOK * H * 2;        // scores 256 KiB
  constexpr size_t OFF_RF   = OFF_SC + (size_t)NTOK * 4;            // rf 32 KiB
  constexpr size_t OFF_WT   = OFF_RF + (size_t)NREG * H * 4;        // wts 256 KiB
  constexpr size_t OFF_SE   = OFF_WT + (size_t)NTOK * 4;            // se 32 KiB
  constexpr size_t OFF_SS   = OFF_SE + (size_t)NREG * H * 4;        // ss 64 B

  unsigned short* W1t  = (unsigned short*)(ws + OFF_W1T);
  unsigned short* Wa1t = (unsigned short*)(ws + OFF_WA1T);
  unsigned short* Eb   = (unsigned short*)(ws + OFF_EB);
  float* scores = (float*)(ws + OFF_SC);
  float* rf     = (float*)(ws + OFF_RF);
  float* wts    = (float*)(ws + OFF_WT);
  float* se     = (float*)(ws + OFF_SE);
  float* ssb    = (float*)(ws + OFF_SS);

  // rf is the only remaining atomic accumulator (k2 writes scores directly now)
  hipMemsetAsync(rf, 0, (size_t)NREG * H * 4, stream);

  k0_prep<<<(DIN * H + HH * H) / 256, 256, 0, stream>>>(W1, Wa1, W1t, Wa1t);
  k1_gemm1<<<512, 512, 0, stream>>>(X, W1t, b1, Eb);
  k2_gemm2<<<512, 512, 0, stream>>>(Eb, Wa1t, ba1, Wa2, scores);
  k3a_softmax<<<NREG, 256, 0, stream>>>(scores, wts);
  k3b_wsum<<<dim3(32, NREG), 256, 0, stream>>>(Eb, wts, rf);
  k4a_slide<<<NREG, 256, 0, stream>>>(rf, Ws, bs, se);
  k4b_sscore<<<NREG, 256, 0, stream>>>(se, Wsa1, bsa1, Wsa2, bsa2, ssb);
  k4c_final<<<1, 256, 0, stream>>>(se, ssb, Wc1, bc1, Wc2, bc2, out);
}

// Round 3
// 619.808 us; speedup vs baseline: 1.0075x; 1.0075x over previous
//
#include <hip/hip_runtime.h>

// ---------------- constants ----------------
#define NTOK 65536
#define DIN  1024
#define H    512
#define HH   256
#define NREG 16
#define MPR  4096   // patches per region = NTOK/NREG

// ---------------- helpers ----------------
__device__ __forceinline__ unsigned short f2bf(float f) {
  unsigned u = __float_as_uint(f);
  u += 0x7fffu + ((u >> 16) & 1u);   // RNE
  return (unsigned short)(u >> 16);
}
__device__ __forceinline__ float bf2f(unsigned short s) {
  return __uint_as_float(((unsigned)s) << 16);
}
__device__ __forceinline__ float gelu_exact(float x) {
  return 0.5f * x * (1.0f + erff(x * 0.70710678118654752440f));
}
__device__ __forceinline__ unsigned cvt_pk_bf16(float lo, float hi) {
  unsigned r;
  asm("v_cvt_pk_bf16_f32 %0, %1, %2" : "=v"(r) : "v"(lo), "v"(hi));
  return r;
}
__device__ __forceinline__ unsigned short f2bf_hw(float f) {
  unsigned r;
  asm("v_cvt_pk_bf16_f32 %0, %1, %2" : "=v"(r) : "v"(f), "v"(f));
  return (unsigned short)r;
}
// fast tanh: 1 - 2/(exp(2x)+1); monotone, saturates to ±1, no NaN at |x|→inf
__device__ __forceinline__ float fast_tanh(float x) {
  float e = __expf(2.0f * x);
  return 1.0f - 2.0f * __builtin_amdgcn_rcpf(e + 1.0f);
}

typedef __attribute__((ext_vector_type(8))) short shortx8;       // 8 bf16 (4 VGPRs)
typedef __attribute__((ext_vector_type(4))) float floatx4;       // 4 fp32
typedef __attribute__((ext_vector_type(4))) unsigned int uintx4; // 16B store

__device__ __forceinline__ void gl_lds16(const void* g, void* l) {
  __builtin_amdgcn_global_load_lds(
      (const __attribute__((address_space(1))) void*)g,
      (__attribute__((address_space(3))) void*)l, 16, 0, 0);
}

// counted waits (rule #18: sched_barrier(0) right after each asm wait)
#define WAITVM(N)                                            \
  do {                                                       \
    asm volatile("s_waitcnt vmcnt(" #N ")" ::: "memory");    \
    __builtin_amdgcn_sched_barrier(0);                       \
  } while (0)
#define WAITLGKM0                                            \
  do {                                                       \
    asm volatile("s_waitcnt lgkmcnt(0)" ::: "memory");       \
    __builtin_amdgcn_sched_barrier(0);                       \
  } while (0)

// chunk-XOR swizzle (verified: bank conflicts -> 0)
__device__ __forceinline__ int swz8(int row, int seg) {
  return (row * 4 + (seg ^ ((row >> 1) & 3))) * 8;  // short index of chunk start
}

// ---------------- K0: weight transpose + bf16 convert ----------------
__global__ __launch_bounds__(256) void k0_prep(const float* __restrict__ W1,
                                               const float* __restrict__ Wa1,
                                               unsigned short* __restrict__ W1t,
                                               unsigned short* __restrict__ Wa1t) {
  int idx = blockIdx.x * 256 + threadIdx.x;
  if (idx < DIN * H) {                 // 524288
    int n = idx >> 10, k = idx & 1023; // W1t[n][k] = W1[k][n]
    W1t[idx] = f2bf(W1[k * H + n]);
  } else {
    int i2 = idx - DIN * H;            // < 131072
    int n = i2 >> 9, k = i2 & 511;     // Wa1t[n][k] = Wa1[k][n]
    Wa1t[i2] = f2bf(Wa1[k * HH + n]);
  }
}

// ---------------- K1: Eb = GELU(X @ W1 + b1), bf16 out ----------------
// M=65536, K=1024, N=512(full). BM=128, BN=512, BK=32. grid(512), 512 thr (8 waves 2x4).
// 3-buffer, depth-2 prefetch, RAW s_barrier + counted vmcnt (never drains in-flight
// next-next stage). Steady-state: 4 B-gl_lds always in flight across the barrier.
__global__ __launch_bounds__(512) void k1_gemm1(const float* __restrict__ X,
                                                const unsigned short* __restrict__ W1t,
                                                const float* __restrict__ b1,
                                                unsigned short* __restrict__ Eb) {
  __shared__ __align__(16) short lA[3][128 * 32];  // 3 x 8 KB
  __shared__ __align__(16) short lB[3][512 * 32];  // 3 x 32 KB
  const int tid = threadIdx.x;
  const int rowBase = blockIdx.x * 128;
  const int lane = tid & 63;
  const int wave = tid >> 6;                // 0..7
  const int wr = wave >> 2, wc = wave & 3;  // 2x4 waves: each 64 rows x 128 cols
  const int l15 = lane & 15, quad = lane >> 4;

  floatx4 acc[4][8] = {};

  // loop-invariant LDS fragment offsets (shorts)
  int offA[4], offB[8];
#pragma unroll
  for (int i = 0; i < 4; i++) offA[i] = swz8(wr * 64 + i * 16 + l15, quad);
#pragma unroll
  for (int j = 0; j < 8; j++) offB[j] = swz8(wc * 128 + j * 16 + l15, quad);

  // A: thread owns (row=tid>>2, seg=tid&3): 8 fp32 -> 16B bf16, write-late into lA
  const int arow = tid >> 2, aseg = tid & 3;
  const float* aPtr = X + (size_t)(rowBase + arow) * DIN + aseg * 8;
  const int aOff = swz8(arow, aseg);

  // B: 4 chunks/thread, pre-swizzled global source, linear LDS dest
  const unsigned short* bPS[4];
  int bDst[4];
#pragma unroll
  for (int s = 0; s < 4; s++) {
    int c = tid + s * 512;
    int n = c >> 2;
    int seg = (c & 3) ^ ((n >> 1) & 3);
    bPS[s] = W1t + (size_t)n * DIN + seg * 8;
    bDst[s] = c * 8;
  }

  // ---- prologue: A(0) regs; B(0),B(1) gl_lds; cvt+write A(0); wait B(0); barrier
  {
    floatx4 p0 = __builtin_nontemporal_load((const floatx4*)aPtr);
    floatx4 p1 = __builtin_nontemporal_load((const floatx4*)aPtr + 1);
    aPtr += 32;
#pragma unroll
    for (int s = 0; s < 4; s++) gl_lds16(bPS[s], &lB[0][bDst[s]]);
#pragma unroll
    for (int s = 0; s < 4; s++) gl_lds16(bPS[s] + 32, &lB[1][bDst[s]]);
#pragma unroll
    for (int s = 0; s < 4; s++) bPS[s] += 64;
    uintx4 u;  // compiler inserts vmcnt(8) here for p0/p1 use — no full drain
    u[0] = cvt_pk_bf16(p0[0], p0[1]);
    u[1] = cvt_pk_bf16(p0[2], p0[3]);
    u[2] = cvt_pk_bf16(p1[0], p1[1]);
    u[3] = cvt_pk_bf16(p1[2], p1[3]);
    *(uintx4*)(&lA[0][aOff]) = u;
    WAITVM(4);   // B(0) landed (keep B(1) in flight)
    WAITLGKM0;   // A(0) ds_write visible
    __builtin_amdgcn_s_barrier();
  }

#define K1_MFMA                                                                  \
  _Pragma("unroll") for (int i = 0; i < 4; i++)                                  \
      _Pragma("unroll") for (int j = 0; j < 8; j++)                              \
          acc[i][j] = __builtin_amdgcn_mfma_f32_16x16x32_bf16(aF[i], bF[j],      \
                                                              acc[i][j], 0, 0, 0);

#define K1_STEP(CUR, ANB, SB, DO_A, DO_B, AWAIT)                                 \
  do {                                                                           \
    shortx8 aF[4], bF[8];                                                        \
    _Pragma("unroll") for (int i = 0; i < 4; i++)                                \
        aF[i] = *(const shortx8*)(&lA[CUR][offA[i]]);                            \
    _Pragma("unroll") for (int j = 0; j < 8; j++)                                \
        bF[j] = *(const shortx8*)(&lB[CUR][offB[j]]);                            \
    floatx4 p0, p1;                                                              \
    if (DO_A) {                                                                  \
      p0 = __builtin_nontemporal_load((const floatx4*)aPtr);                     \
      p1 = __builtin_nontemporal_load((const floatx4*)aPtr + 1);                 \
      aPtr += 32;                                                                \
    }                                                                            \
    if (DO_B) {                                                                  \
      _Pragma("unroll") for (int s = 0; s < 4; s++) {                            \
        gl_lds16(bPS[s], &lB[SB][bDst[s]]);                                      \
        bPS[s] += 32;                                                            \
      }                                                                          \
    }                                                                            \
    WAITLGKM0;                                                                   \
    K1_MFMA;                                                                     \
    if (DO_A) {                                                                  \
      AWAIT; /* A regs ready; keeps newest B stage in flight */                  \
      uintx4 u;                                                                  \
      u[0] = cvt_pk_bf16(p0[0], p0[1]);                                          \
      u[1] = cvt_pk_bf16(p0[2], p0[3]);                                          \
      u[2] = cvt_pk_bf16(p1[0], p1[1]);                                          \
      u[3] = cvt_pk_bf16(p1[2], p1[3]);                                          \
      *(uintx4*)(&lA[ANB][aOff]) = u;                                            \
    }                                                                            \
    WAITLGKM0;                                                                   \
    __builtin_amdgcn_s_barrier();                                                \
  } while (0)

  // steady: t = 0..29 (stages t+2 <= 31, loads A(t+1) <= A(30))
#pragma unroll 1
  for (int tt = 0; tt < 10; ++tt) {
    K1_STEP(0, 1, 2, true, true, WAITVM(4));
    K1_STEP(1, 2, 0, true, true, WAITVM(4));
    K1_STEP(2, 0, 1, true, true, WAITVM(4));
  }
  // t = 30: cur=0, load A(31), no B stage; must drain B(31) too
  K1_STEP(0, 1, 2, true, false, WAITVM(0));
  // t = 31: cur=1, compute only
  {
    shortx8 aF[4], bF[8];
#pragma unroll
    for (int i = 0; i < 4; i++) aF[i] = *(const shortx8*)(&lA[1][offA[i]]);
#pragma unroll
    for (int j = 0; j < 8; j++) bF[j] = *(const shortx8*)(&lB[1][offB[j]]);
    WAITLGKM0;
    K1_MFMA;
  }
  __builtin_amdgcn_s_barrier();  // all frag reads done before LDS reuse

  // ---- epilogue: bias + GELU; LDS transpose so each lane stores 16B coalesced.
  // Wave-private 8 KB region (32 rows x 128 cols bf16), two halves of the 64 rows.
  short* lE = &lB[0][0];  // 64 KB used (8 waves x 8 KB) inside the 96 KB lB
  const int row0 = rowBase + wr * 64;
  float bias[8];
#pragma unroll
  for (int j = 0; j < 8; j++) bias[j] = b1[wc * 128 + j * 16 + l15];
#pragma unroll
  for (int h = 0; h < 2; h++) {
    WAITLGKM0;  // previous half's ds_reads retired before overwrite
#pragma unroll
    for (int il = 0; il < 2; il++)
#pragma unroll
      for (int j = 0; j < 8; j++)
#pragma unroll
        for (int v = 0; v < 4; v++) {
          int r = il * 16 + quad * 4 + v;        // 0..31
          int col = j * 16 + l15;                // 0..127
          float x = acc[2 * h + il][j][v] + bias[j];
          int chunk = (col >> 3) ^ (r & 7);
          lE[wave * 4096 + r * 128 + chunk * 8 + (col & 7)] =
              (short)f2bf_hw(gelu_exact(x));
        }
    WAITLGKM0;  // writes visible (same-wave region, no barrier needed)
#pragma unroll
    for (int rr = 0; rr < 8; rr++) {
      int r = rr * 4 + quad;
      int chunk = l15 ^ (r & 7);
      shortx8 val = *(const shortx8*)(&lE[wave * 4096 + r * 128 + chunk * 8]);
      *(shortx8*)(&Eb[(size_t)(row0 + h * 32 + r) * H + wc * 128 + l15 * 8]) = val;
    }
  }
}

// ---------------- K2: scores = tanh(Eb @ Wa1 + ba1) . Wa2  (fused, full-N) ----------------
// M=65536, K=512, N=256(full). BM=128, BN=256, BK=32. grid(512), 512 thr (8 waves 2x4).
// Same 3-buffer counted-vmcnt structure; 3 gl_lds/thread/step, steady wait vmcnt(3).
__global__ __launch_bounds__(512) void k2_gemm2(const unsigned short* __restrict__ Eb,
                                                const unsigned short* __restrict__ Wa1t,
                                                const float* __restrict__ ba1,
                                                const float* __restrict__ Wa2,
                                                float* __restrict__ scores) {
  __shared__ __align__(16) short lA[3][128 * 32];  // 24 KB
  __shared__ __align__(16) short lB[3][256 * 32];  // 48 KB
  __shared__ float part[4][128];
  const int tid = threadIdx.x;
  const int rowBase = blockIdx.x * 128;
  const int lane = tid & 63;
  const int wave = tid >> 6;
  const int wr = wave >> 2, wc = wave & 3;  // each wave: 64 rows x 64 cols
  const int l15 = lane & 15, quad = lane >> 4;

  floatx4 acc[4][4] = {};

  int offA[4], offB[4];
#pragma unroll
  for (int i = 0; i < 4; i++) offA[i] = swz8(wr * 64 + i * 16 + l15, quad);
#pragma unroll
  for (int j = 0; j < 4; j++) offB[j] = swz8(wc * 64 + j * 16 + l15, quad);

  // A: 1 chunk/thread; B: 2 chunks/thread
  const unsigned short* aPS;
  int aDst;
  {
    int c = tid, n = c >> 2;
    int seg = (c & 3) ^ ((n >> 1) & 3);
    aPS = Eb + (size_t)(rowBase + n) * H + seg * 8;
    aDst = c * 8;
  }
  const unsigned short* bPS[2];
  int bDst[2];
#pragma unroll
  for (int s = 0; s < 2; s++) {
    int c = tid + s * 512, n = c >> 2;
    int seg = (c & 3) ^ ((n >> 1) & 3);
    bPS[s] = Wa1t + (size_t)n * H + seg * 8;
    bDst[s] = c * 8;
  }

  // prologue: stage(0), stage(1); wait tile0; barrier
  gl_lds16(aPS, &lA[0][aDst]);
  gl_lds16(bPS[0], &lB[0][bDst[0]]);
  gl_lds16(bPS[1], &lB[0][bDst[1]]);
  gl_lds16(aPS + 32, &lA[1][aDst]);
  gl_lds16(bPS[0] + 32, &lB[1][bDst[0]]);
  gl_lds16(bPS[1] + 32, &lB[1][bDst[1]]);
  aPS += 64; bPS[0] += 64; bPS[1] += 64;
  WAITVM(3);  // tile 0 landed (keep tile 1's 3 in flight)
  __builtin_amdgcn_s_barrier();

#define K2_MFMA                                                                  \
  _Pragma("unroll") for (int i = 0; i < 4; i++)                                  \
      _Pragma("unroll") for (int j = 0; j < 4; j++)                              \
          acc[i][j] = __builtin_amdgcn_mfma_f32_16x16x32_bf16(aF[i], bF[j],      \
                                                              acc[i][j], 0, 0, 0);

#define K2_STEP(CUR, SB, DO_B, BW)                                               \
  do {                                                                           \
    shortx8 aF[4], bF[4];                                                        \
    _Pragma("unroll") for (int i = 0; i < 4; i++)                                \
        aF[i] = *(const shortx8*)(&lA[CUR][offA[i]]);                            \
    _Pragma("unroll") for (int j = 0; j < 4; j++)                                \
        bF[j] = *(const shortx8*)(&lB[CUR][offB[j]]);                            \
    if (DO_B) {                                                                  \
      gl_lds16(aPS, &lA[SB][aDst]);                                              \
      gl_lds16(bPS[0], &lB[SB][bDst[0]]);                                        \
      gl_lds16(bPS[1], &lB[SB][bDst[1]]);                                        \
      aPS += 32; bPS[0] += 32; bPS[1] += 32;                                     \
    }                                                                            \
    WAITLGKM0;                                                                   \
    K2_MFMA;                                                                     \
    BW;                                                                          \
    __builtin_amdgcn_s_barrier();                                                \
  } while (0)

  // steady t = 0..11
#pragma unroll 1
  for (int tt = 0; tt < 4; ++tt) {
    K2_STEP(0, 2, true, WAITVM(3));
    K2_STEP(1, 0, true, WAITVM(3));
    K2_STEP(2, 1, true, WAITVM(3));
  }
  K2_STEP(0, 2, true, WAITVM(3));   // t=12
  K2_STEP(1, 0, true, WAITVM(3));   // t=13
  K2_STEP(2, 1, false, WAITVM(0));  // t=14: no stage; drain tile 15
  {                                  // t=15: compute only
    shortx8 aF[4], bF[4];
#pragma unroll
    for (int i = 0; i < 4; i++) aF[i] = *(const shortx8*)(&lA[0][offA[i]]);
#pragma unroll
    for (int j = 0; j < 4; j++) bF[j] = *(const shortx8*)(&lB[0][offB[j]]);
    WAITLGKM0;
    K2_MFMA;
  }

  // epilogue: p[i][v] = sum over this wave's 64 cols of tanh(acc + ba1) * Wa2
  float p[4][4];
#pragma unroll
  for (int i = 0; i < 4; i++)
#pragma unroll
    for (int v = 0; v < 4; v++) p[i][v] = 0.0f;
#pragma unroll
  for (int j = 0; j < 4; j++) {
    int col = wc * 64 + j * 16 + l15;
    float bias = ba1[col];
    float wa2 = Wa2[col];
#pragma unroll
    for (int i = 0; i < 4; i++)
#pragma unroll
      for (int v = 0; v < 4; v++)
        p[i][v] += fast_tanh(acc[i][j][v] + bias) * wa2;
  }
#pragma unroll
  for (int i = 0; i < 4; i++)
#pragma unroll
    for (int v = 0; v < 4; v++) {
      float t = p[i][v];
      t += __shfl_xor(t, 1, 16);
      t += __shfl_xor(t, 2, 16);
      t += __shfl_xor(t, 4, 16);
      t += __shfl_xor(t, 8, 16);
      p[i][v] = t;
    }
  if (l15 == 0) {
#pragma unroll
    for (int i = 0; i < 4; i++)
#pragma unroll
      for (int v = 0; v < 4; v++)
        part[wc][wr * 64 + i * 16 + quad * 4 + v] = p[i][v];
  }
  __syncthreads();
  if (tid < 128)
    scores[rowBase + tid] = part[0][tid] + part[1][tid] + part[2][tid] + part[3][tid];
}

// ---------------- K3a: per-region softmax weights ----------------
__global__ __launch_bounds__(256) void k3a_softmax(const float* __restrict__ scores,
                                                   float* __restrict__ wts) {
  const int r = blockIdx.x, tid = threadIdx.x;
  __shared__ float red[256];
  float m = -1e30f;
  for (int j = tid; j < MPR; j += 256) m = fmaxf(m, scores[r + NREG * j]);
  red[tid] = m;
  __syncthreads();
  for (int s = 128; s > 0; s >>= 1) {
    if (tid < s) red[tid] = fmaxf(red[tid], red[tid + s]);
    __syncthreads();
  }
  float mx = red[0];
  __syncthreads();
  float sum = 0.0f;
  for (int j = tid; j < MPR; j += 256) sum += expf(scores[r + NREG * j] - mx);
  red[tid] = sum;
  __syncthreads();
  for (int s = 128; s > 0; s >>= 1) {
    if (tid < s) red[tid] += red[tid + s];
    __syncthreads();
  }
  float inv = 1.0f / red[0];
  for (int j = tid; j < MPR; j += 256)
    wts[r + NREG * j] = expf(scores[r + NREG * j] - mx) * inv;
}

// ---------------- K3b: region_features[r][h] = sum_m w * Eb ----------------
__global__ __launch_bounds__(256) void k3b_wsum(const unsigned short* __restrict__ Eb,
                                                const float* __restrict__ wts,
                                                float* __restrict__ rf) {
  const int r = blockIdx.y;
  const int mc = blockIdx.x;
  const int tid = threadIdx.x;
  float a0 = 0.0f, a1 = 0.0f;
  for (int j = mc * 128; j < mc * 128 + 128; j++) {
    int n = r + NREG * j;
    float w = wts[n];
    unsigned v = *(const unsigned*)(Eb + (size_t)n * H + tid * 2);
    a0 += w * bf2f((unsigned short)(v & 0xffffu));
    a1 += w * bf2f((unsigned short)(v >> 16));
  }
  atomicAdd(&rf[r * H + tid * 2], a0);
  atomicAdd(&rf[r * H + tid * 2 + 1], a1);
}

// ---------------- K4a: slide_emb = GELU(rf @ Ws + bs) ----------------
__global__ __launch_bounds__(256) void k4a_slide(const float* __restrict__ rf,
                                                 const float* __restrict__ Ws,
                                                 const float* __restrict__ bs,
                                                 float* __restrict__ se) {
  const int r = blockIdx.x, tid = threadIdx.x;
  __shared__ float lrf[H];
  lrf[tid] = rf[r * H + tid];
  lrf[tid + 256] = rf[r * H + tid + 256];
  __syncthreads();
  float a0 = 0.0f, a1 = 0.0f;
  for (int k = 0; k < H; k++) {
    float x = lrf[k];
    a0 += x * Ws[k * H + tid];
    a1 += x * Ws[k * H + tid + 256];
  }
  se[r * H + tid] = gelu_exact(a0 + bs[tid]);
  se[r * H + tid + 256] = gelu_exact(a1 + bs[tid + 256]);
}

// ---------------- K4b: sscore[r] = tanh(se @ Wsa1 + bsa1) . Wsa2 + bsa2 ----------------
__global__ __launch_bounds__(256) void k4b_sscore(const float* __restrict__ se,
                                                  const float* __restrict__ Wsa1,
                                                  const float* __restrict__ bsa1,
                                                  const float* __restrict__ Wsa2,
                                                  const float* __restrict__ bsa2,
                                                  float* __restrict__ ss) {
  const int r = blockIdx.x, tid = threadIdx.x;
  __shared__ float lse[H];
  __shared__ float red[256];
  lse[tid] = se[r * H + tid];
  lse[tid + 256] = se[r * H + tid + 256];
  __syncthreads();
  float a = 0.0f;
  for (int k = 0; k < H; k++) a += lse[k] * Wsa1[k * HH + tid];
  red[tid] = tanhf(a + bsa1[tid]) * Wsa2[tid];
  __syncthreads();
  for (int s = 128; s > 0; s >>= 1) {
    if (tid < s) red[tid] += red[tid + s];
    __syncthreads();
  }
  if (tid == 0) ss[r] = red[0] + bsa2[0];
}

// ---------------- K4c: softmax over regions + classifier ----------------
__global__ __launch_bounds__(256) void k4c_final(const float* __restrict__ se,
                                                 const float* __restrict__ ss,
                                                 const float* __restrict__ Wc1,
                                                 const float* __restrict__ bc1,
                                                 const float* __restrict__ Wc2,
                                                 const float* __restrict__ bc2,
                                                 float* __restrict__ out) {
  const int tid = threadIdx.x;
  __shared__ float srep[H];
  __shared__ float r0[256], r1[256];
  float mx = -1e30f;
  for (int i = 0; i < NREG; i++) mx = fmaxf(mx, ss[i]);
  float wv[NREG];
  float den = 0.0f;
  for (int i = 0; i < NREG; i++) { wv[i] = expf(ss[i] - mx); den += wv[i]; }
  float inv = 1.0f / den;
  float s0 = 0.0f, s1 = 0.0f;
  for (int i = 0; i < NREG; i++) {
    float w = wv[i] * inv;
    s0 += w * se[i * H + tid];
    s1 += w * se[i * H + tid + 256];
  }
  srep[tid] = s0;
  srep[tid + 256] = s1;
  __syncthreads();
  float a = 0.0f;
  for (int k = 0; k < H; k++) a += srep[k] * Wc1[k * HH + tid];
  float g = gelu_exact(a + bc1[tid]);
  r0[tid] = g * Wc2[tid * 2];
  r1[tid] = g * Wc2[tid * 2 + 1];
  __syncthreads();
  for (int s = 128; s > 0; s >>= 1) {
    if (tid < s) { r0[tid] += r0[tid + s]; r1[tid] += r1[tid + s]; }
    __syncthreads();
  }
  if (tid == 0) {
    out[0] = r0[0] + bc2[0];
    out[1] = r1[0] + bc2[1];
  }
}

// ---------------- launcher ----------------
extern "C" void kernel_launch(void* const* d_in, const int* in_sizes, int n_in,
                              void* d_out, int out_size, void* d_ws, size_t ws_size,
                              hipStream_t stream) {
  const float* X    = (const float*)d_in[0];
  const float* W1   = (const float*)d_in[1];
  const float* b1   = (const float*)d_in[2];
  const float* Wa1  = (const float*)d_in[3];
  const float* ba1  = (const float*)d_in[4];
  const float* Wa2  = (const float*)d_in[5];
  // d_in[6] = ba2: constant shift inside softmax -> no effect, unused
  const float* Ws   = (const float*)d_in[7];
  const float* bs   = (const float*)d_in[8];
  const float* Wsa1 = (const float*)d_in[9];
  const float* bsa1 = (const float*)d_in[10];
  const float* Wsa2 = (const float*)d_in[11];
  const float* bsa2 = (const float*)d_in[12];
  const float* Wc1  = (const float*)d_in[13];
  const float* bc1  = (const float*)d_in[14];
  const float* Wc2  = (const float*)d_in[15];
  const float* bc2  = (const float*)d_in[16];
  float* out = (float*)d_out;

  char* ws = (char*)d_ws;
  constexpr size_t OFF_W1T  = 0;                                    // 1 MiB
  constexpr size_t OFF_WA1T = OFF_W1T + (size_t)H * DIN * 2;        // +256 KiB
  constexpr size_t OFF_EB   = OFF_WA1T + (size_t)HH * H * 2;        // +64 MiB
  constexpr size_t OFF_SC   = OFF_EB + (size_t)NTOK * H * 2;        // scores 256 KiB
  constexpr size_t OFF_RF   = OFF_SC + (size_t)NTOK * 4;            // rf 32 KiB
  constexpr size_t OFF_WT   = OFF_RF + (size_t)NREG * H * 4;        // wts 256 KiB
  constexpr size_t OFF_SE   = OFF_WT + (size_t)NTOK * 4;            // se 32 KiB
  constexpr size_t OFF_SS   = OFF_SE + (size_t)NREG * H * 4;        // ss 64 B

  unsigned short* W1t  = (unsigned short*)(ws + OFF_W1T);
  unsigned short* Wa1t = (unsigned short*)(ws + OFF_WA1T);
  unsigned short* Eb   = (unsigned short*)(ws + OFF_EB);
  float* scores = (float*)(ws + OFF_SC);
  float* rf     = (float*)(ws + OFF_RF);
  float* wts    = (float*)(ws + OFF_WT);
  float* se     = (float*)(ws + OFF_SE);
  float* ssb    = (float*)(ws + OFF_SS);

  hipMemsetAsync(rf, 0, (size_t)NREG * H * 4, stream);

  k0_prep<<<(DIN * H + HH * H) / 256, 256, 0, stream>>>(W1, Wa1, W1t, Wa1t);
  k1_gemm1<<<512, 512, 0, stream>>>(X, W1t, b1, Eb);
  k2_gemm2<<<512, 512, 0, stream>>>(Eb, Wa1t, ba1, Wa2, scores);
  k3a_softmax<<<NREG, 256, 0, stream>>>(scores, wts);
  k3b_wsum<<<dim3(32, NREG), 256, 0, stream>>>(Eb, wts, rf);
  k4a_slide<<<NREG, 256, 0, stream>>>(rf, Ws, bs, se);
  k4b_sscore<<<NREG, 256, 0, stream>>>(se, Wsa1, bsa1, Wsa2, bsa2, ssb);
  k4c_final<<<1, 256, 0, stream>>>(se, ssb, Wc1, bc1, Wc2, bc2, out);
}

// Round 4
// 594.051 us; speedup vs baseline: 1.0512x; 1.0434x over previous
//
#include <hip/hip_runtime.h>

// ---------------- constants ----------------
#define NTOK 65536
#define DIN  1024
#define H    512
#define HH   256
#define NREG 16
#define MPR  4096   // patches per region = NTOK/NREG

// ---------------- helpers ----------------
__device__ __forceinline__ unsigned short f2bf(float f) {
  unsigned u = __float_as_uint(f);
  u += 0x7fffu + ((u >> 16) & 1u);   // RNE
  return (unsigned short)(u >> 16);
}
__device__ __forceinline__ float bf2f(unsigned short s) {
  return __uint_as_float(((unsigned)s) << 16);
}
__device__ __forceinline__ float gelu_exact(float x) {
  return 0.5f * x * (1.0f + erff(x * 0.70710678118654752440f));
}
__device__ __forceinline__ unsigned cvt_pk_bf16(float lo, float hi) {
  unsigned r;
  asm("v_cvt_pk_bf16_f32 %0, %1, %2" : "=v"(r) : "v"(lo), "v"(hi));
  return r;
}
__device__ __forceinline__ unsigned short f2bf_hw(float f) {
  unsigned r;
  asm("v_cvt_pk_bf16_f32 %0, %1, %2" : "=v"(r) : "v"(f), "v"(f));
  return (unsigned short)r;
}
// fast tanh: 1 - 2/(exp(2x)+1); monotone, saturates to ±1, no NaN at |x|→inf
__device__ __forceinline__ float fast_tanh(float x) {
  float e = __expf(2.0f * x);
  return 1.0f - 2.0f * __builtin_amdgcn_rcpf(e + 1.0f);
}

typedef __attribute__((ext_vector_type(8))) short shortx8;       // 8 bf16 (4 VGPRs)
typedef __attribute__((ext_vector_type(4))) float floatx4;       // 4 fp32
typedef __attribute__((ext_vector_type(4))) unsigned int uintx4; // 16B store

__device__ __forceinline__ void gl_lds16(const void* g, void* l) {
  __builtin_amdgcn_global_load_lds(
      (const __attribute__((address_space(1))) void*)g,
      (__attribute__((address_space(3))) void*)l, 16, 0, 0);
}

// counted waits (rule #18: sched_barrier(0) right after each asm wait)
#define WAITVM(N)                                            \
  do {                                                       \
    asm volatile("s_waitcnt vmcnt(" #N ")" ::: "memory");    \
    __builtin_amdgcn_sched_barrier(0);                       \
  } while (0)
#define WAITLGKM0                                            \
  do {                                                       \
    asm volatile("s_waitcnt lgkmcnt(0)" ::: "memory");       \
    __builtin_amdgcn_sched_barrier(0);                       \
  } while (0)

// chunk-XOR swizzle for 4-chunk (64B) rows (verified: bank conflicts -> 0)
__device__ __forceinline__ int swz8(int row, int seg) {
  return (row * 4 + (seg ^ ((row >> 1) & 3))) * 8;  // short index of chunk start
}

// ---------------- K0: weight transpose + bf16 convert ----------------
__global__ __launch_bounds__(256) void k0_prep(const float* __restrict__ W1,
                                               const float* __restrict__ Wa1,
                                               unsigned short* __restrict__ W1t,
                                               unsigned short* __restrict__ Wa1t) {
  int idx = blockIdx.x * 256 + threadIdx.x;
  if (idx < DIN * H) {                 // 524288
    int n = idx >> 10, k = idx & 1023; // W1t[n][k] = W1[k][n]
    W1t[idx] = f2bf(W1[k * H + n]);
  } else {
    int i2 = idx - DIN * H;            // < 131072
    int n = i2 >> 9, k = i2 & 511;     // Wa1t[n][k] = Wa1[k][n]
    Wa1t[i2] = f2bf(Wa1[k * HH + n]);
  }
}

// ---------------- K12: Eb = GELU(X @ W1 + b1)  AND  scores = tanh(Eb@Wa1+ba1).Wa2 ----------------
// Fused: k1's full-N (BM=128, BN=512) GEMM keeps the whole output tile on-chip, so the
// attention-score GEMM (K=512, N=256) runs directly off LDS — k2's dispatch and its
// 64+ MB Eb re-read are eliminated. scores written REGION-MAJOR: scores[r*MPR + j].
__global__ __launch_bounds__(512) void k12_fused(const float* __restrict__ X,
                                                 const unsigned short* __restrict__ W1t,
                                                 const float* __restrict__ b1,
                                                 const unsigned short* __restrict__ Wa1t,
                                                 const float* __restrict__ ba1,
                                                 const float* __restrict__ Wa2,
                                                 unsigned short* __restrict__ Eb,
                                                 float* __restrict__ scores) {
  // LDS union: main loop uses lA[3](24K)+lB[3](96K)=120K; post-phase uses
  // lT(128K gelu'd tile) + wB(16K score-B stage) + part(2K) = 146K.
  __shared__ __align__(16) char sh[149504];
  short (*lA)[128 * 32] = (short (*)[128 * 32])(sh);            // 3 x 8 KB
  short (*lB)[512 * 32] = (short (*)[512 * 32])(sh + 24576);    // 3 x 32 KB
  short* lT   = (short*)sh;                                     // 128 rows x 512 cols
  short* wB   = (short*)(sh + 131072);                          // 256 x 32 bf16
  float* part = (float*)(sh + 147456);                          // 4 x 128 f32

  const int tid = threadIdx.x;
  const int rowBase = blockIdx.x * 128;
  const int lane = tid & 63;
  const int wave = tid >> 6;                // 0..7
  const int wr = wave >> 2, wc = wave & 3;  // 2x4 waves: each 64 rows x 128 cols
  const int l15 = lane & 15, quad = lane >> 4;

  floatx4 acc[4][8] = {};

  int offA[4], offB[8];
#pragma unroll
  for (int i = 0; i < 4; i++) offA[i] = swz8(wr * 64 + i * 16 + l15, quad);
#pragma unroll
  for (int j = 0; j < 8; j++) offB[j] = swz8(wc * 128 + j * 16 + l15, quad);

  // A: thread owns (row=tid>>2, seg=tid&3): 8 fp32 -> 16B bf16, write-late into lA
  const int arow = tid >> 2, aseg = tid & 3;
  const float* aPtr = X + (size_t)(rowBase + arow) * DIN + aseg * 8;
  const int aOff = swz8(arow, aseg);

  // B: 4 chunks/thread, pre-swizzled global source, linear LDS dest
  const unsigned short* bPS[4];
  int bDst[4];
#pragma unroll
  for (int s = 0; s < 4; s++) {
    int c = tid + s * 512;
    int n = c >> 2;
    int seg = (c & 3) ^ ((n >> 1) & 3);
    bPS[s] = W1t + (size_t)n * DIN + seg * 8;
    bDst[s] = c * 8;
  }

  // ---- prologue: A(0) regs; B(0),B(1) gl_lds; cvt+write A(0); wait B(0); barrier
  {
    floatx4 p0 = __builtin_nontemporal_load((const floatx4*)aPtr);
    floatx4 p1 = __builtin_nontemporal_load((const floatx4*)aPtr + 1);
    aPtr += 32;
#pragma unroll
    for (int s = 0; s < 4; s++) gl_lds16(bPS[s], &lB[0][bDst[s]]);
#pragma unroll
    for (int s = 0; s < 4; s++) gl_lds16(bPS[s] + 32, &lB[1][bDst[s]]);
#pragma unroll
    for (int s = 0; s < 4; s++) bPS[s] += 64;
    uintx4 u;
    u[0] = cvt_pk_bf16(p0[0], p0[1]);
    u[1] = cvt_pk_bf16(p0[2], p0[3]);
    u[2] = cvt_pk_bf16(p1[0], p1[1]);
    u[3] = cvt_pk_bf16(p1[2], p1[3]);
    *(uintx4*)(&lA[0][aOff]) = u;
    WAITVM(4);
    WAITLGKM0;
    __builtin_amdgcn_s_barrier();
  }

#define K1_MFMA                                                                  \
  __builtin_amdgcn_s_setprio(1);                                                 \
  _Pragma("unroll") for (int i = 0; i < 4; i++)                                  \
      _Pragma("unroll") for (int j = 0; j < 8; j++)                              \
          acc[i][j] = __builtin_amdgcn_mfma_f32_16x16x32_bf16(aF[i], bF[j],      \
                                                              acc[i][j], 0, 0, 0); \
  __builtin_amdgcn_s_setprio(0);

#define K1_STEP(CUR, ANB, SB, DO_A, DO_B, AWAIT)                                 \
  do {                                                                           \
    shortx8 aF[4], bF[8];                                                        \
    _Pragma("unroll") for (int i = 0; i < 4; i++)                                \
        aF[i] = *(const shortx8*)(&lA[CUR][offA[i]]);                            \
    _Pragma("unroll") for (int j = 0; j < 8; j++)                                \
        bF[j] = *(const shortx8*)(&lB[CUR][offB[j]]);                            \
    floatx4 p0, p1;                                                              \
    if (DO_A) {                                                                  \
      p0 = __builtin_nontemporal_load((const floatx4*)aPtr);                     \
      p1 = __builtin_nontemporal_load((const floatx4*)aPtr + 1);                 \
      aPtr += 32;                                                                \
    }                                                                            \
    if (DO_B) {                                                                  \
      _Pragma("unroll") for (int s = 0; s < 4; s++) {                            \
        gl_lds16(bPS[s], &lB[SB][bDst[s]]);                                      \
        bPS[s] += 32;                                                            \
      }                                                                          \
    }                                                                            \
    WAITLGKM0;                                                                   \
    K1_MFMA;                                                                     \
    if (DO_A) {                                                                  \
      AWAIT;                                                                     \
      uintx4 u;                                                                  \
      u[0] = cvt_pk_bf16(p0[0], p0[1]);                                          \
      u[1] = cvt_pk_bf16(p0[2], p0[3]);                                          \
      u[2] = cvt_pk_bf16(p1[0], p1[1]);                                          \
      u[3] = cvt_pk_bf16(p1[2], p1[3]);                                          \
      *(uintx4*)(&lA[ANB][aOff]) = u;                                            \
    }                                                                            \
    WAITLGKM0;                                                                   \
    __builtin_amdgcn_s_barrier();                                                \
  } while (0)

#pragma unroll 1
  for (int tt = 0; tt < 10; ++tt) {
    K1_STEP(0, 1, 2, true, true, WAITVM(4));
    K1_STEP(1, 2, 0, true, true, WAITVM(4));
    K1_STEP(2, 0, 1, true, true, WAITVM(4));
  }
  K1_STEP(0, 1, 2, true, false, WAITVM(0));  // t=30
  {                                           // t=31: compute only
    shortx8 aF[4], bF[8];
#pragma unroll
    for (int i = 0; i < 4; i++) aF[i] = *(const shortx8*)(&lA[1][offA[i]]);
#pragma unroll
    for (int j = 0; j < 8; j++) bF[j] = *(const shortx8*)(&lB[1][offB[j]]);
    WAITLGKM0;
    K1_MFMA;
  }
  __builtin_amdgcn_s_barrier();  // all frag reads done; staging LDS now dead

  // ---- write gelu'd bf16 tile into lT: physical chunk = (col>>3) ^ (row&7).
  // Row stride 1024 B; XOR over 8 chunk slots spreads a 16-lane column-read
  // across 32 banks (2 lanes/bank = free).
  {
    const int rl0 = wr * 64;
#pragma unroll
    for (int j = 0; j < 8; j++) {
      int col = wc * 128 + j * 16 + l15;
      float bias = b1[col];
#pragma unroll
      for (int i = 0; i < 4; i++) {
#pragma unroll
        for (int v = 0; v < 4; v++) {
          int r = rl0 + i * 16 + quad * 4 + v;
          float x = acc[i][j][v] + bias;
          lT[r * 512 + (((col >> 3) ^ (r & 7)) << 3) + (col & 7)] =
              (short)f2bf_hw(gelu_exact(x));
        }
      }
    }
  }
  __syncthreads();

  // ---- Eb store: coalesced 16B per lane from lT (stores fly under score-GEMM)
#pragma unroll
  for (int s = 0; s < 16; s++) {
    int c = tid + s * 512;          // 8192 chunks = 128 rows x 64 chunks
    int row = c >> 6, g = c & 63;
    shortx8 val = *(const shortx8*)(&lT[row * 512 + ((g ^ (row & 7)) << 3)]);
    *(shortx8*)(&Eb[(size_t)(rowBase + row) * H + g * 8]) = val;
  }

  // ---- score-GEMM: [128 x 512] (lT) @ Wa1t^T -> [128 x 256], K-steps of 32.
  // 8 waves 2x4: wave tile 64 rows x 64 cols.
  const int wr2 = wave >> 2, wc2 = wave & 3;
  floatx4 acc2[4][4] = {};
  int r2[4];
#pragma unroll
  for (int i = 0; i < 4; i++) r2[i] = wr2 * 64 + i * 16 + l15;
  int offB2[4];
#pragma unroll
  for (int j = 0; j < 4; j++) offB2[j] = swz8(wc2 * 64 + j * 16 + l15, quad);

#pragma unroll 1
  for (int kk = 0; kk < 16; ++kk) {
    __syncthreads();  // wB free (prev step's frag reads done)
#pragma unroll
    for (int s = 0; s < 2; s++) {
      int c = tid + s * 512;      // 1024 chunks = 256 rows x 4 chunks
      int n = c >> 2;
      int seg = (c & 3) ^ ((n >> 1) & 3);
      gl_lds16(Wa1t + (size_t)n * H + kk * 32 + seg * 8, &wB[c * 8]);
    }
    __syncthreads();  // drains vmcnt (wB staged) before reads
    shortx8 aF[4], bF[4];
#pragma unroll
    for (int i = 0; i < 4; i++)
      aF[i] = *(const shortx8*)(&lT[r2[i] * 512 + (((kk * 4 + quad) ^ (r2[i] & 7)) << 3)]);
#pragma unroll
    for (int j = 0; j < 4; j++) bF[j] = *(const shortx8*)(&wB[offB2[j]]);
    __builtin_amdgcn_s_setprio(1);
#pragma unroll
    for (int i = 0; i < 4; i++)
#pragma unroll
      for (int j = 0; j < 4; j++)
        acc2[i][j] = __builtin_amdgcn_mfma_f32_16x16x32_bf16(aF[i], bF[j], acc2[i][j], 0, 0, 0);
    __builtin_amdgcn_s_setprio(0);
  }

  // ---- tanh(acc2 + ba1) . Wa2, reduce over 256 cols, write region-major scores
  float p[4][4];
#pragma unroll
  for (int i = 0; i < 4; i++)
#pragma unroll
    for (int v = 0; v < 4; v++) p[i][v] = 0.0f;
#pragma unroll
  for (int j = 0; j < 4; j++) {
    int col = wc2 * 64 + j * 16 + l15;
    float bias = ba1[col];
    float wa2 = Wa2[col];
#pragma unroll
    for (int i = 0; i < 4; i++)
#pragma unroll
      for (int v = 0; v < 4; v++)
        p[i][v] += fast_tanh(acc2[i][j][v] + bias) * wa2;
  }
#pragma unroll
  for (int i = 0; i < 4; i++)
#pragma unroll
    for (int v = 0; v < 4; v++) {
      float t = p[i][v];
      t += __shfl_xor(t, 1, 16);
      t += __shfl_xor(t, 2, 16);
      t += __shfl_xor(t, 4, 16);
      t += __shfl_xor(t, 8, 16);
      p[i][v] = t;
    }
  if (l15 == 0) {
#pragma unroll
    for (int i = 0; i < 4; i++)
#pragma unroll
      for (int v = 0; v < 4; v++)
        part[wc2 * 128 + wr2 * 64 + i * 16 + quad * 4 + v] = p[i][v];
  }
  __syncthreads();
  if (tid < 128) {
    float s = part[tid] + part[128 + tid] + part[256 + tid] + part[384 + tid];
    int n = rowBase + tid;
    scores[(n & 15) * MPR + (n >> 4)] = s;  // region-major
  }
}

// ---------------- K3a: per-region softmax weights (region-major, coalesced) ----------------
__global__ __launch_bounds__(256) void k3a_softmax(const float* __restrict__ scores,
                                                   float* __restrict__ wts) {
  const int r = blockIdx.x, tid = threadIdx.x;
  const float* sc = scores + r * MPR;
  float* wt = wts + r * MPR;
  __shared__ float red[256];
  float m = -1e30f;
  for (int j = tid; j < MPR; j += 256) m = fmaxf(m, sc[j]);
  red[tid] = m;
  __syncthreads();
  for (int s = 128; s > 0; s >>= 1) {
    if (tid < s) red[tid] = fmaxf(red[tid], red[tid + s]);
    __syncthreads();
  }
  float mx = red[0];
  __syncthreads();
  float sum = 0.0f;
  for (int j = tid; j < MPR; j += 256) sum += expf(sc[j] - mx);
  red[tid] = sum;
  __syncthreads();
  for (int s = 128; s > 0; s >>= 1) {
    if (tid < s) red[tid] += red[tid + s];
    __syncthreads();
  }
  float inv = 1.0f / red[0];
  for (int j = tid; j < MPR; j += 256) wt[j] = expf(sc[j] - mx) * inv;
}

// ---------------- K3b: region_features[r][h] = sum_m w * Eb ----------------
__global__ __launch_bounds__(256) void k3b_wsum(const unsigned short* __restrict__ Eb,
                                                const float* __restrict__ wts,
                                                float* __restrict__ rf) {
  const int r = blockIdx.y;
  const int mc = blockIdx.x;
  const int tid = threadIdx.x;
  float a0 = 0.0f, a1 = 0.0f;
  for (int j = mc * 128; j < mc * 128 + 128; j++) {
    float w = wts[r * MPR + j];
    int n = r + NREG * j;
    unsigned v = *(const unsigned*)(Eb + (size_t)n * H + tid * 2);
    a0 += w * bf2f((unsigned short)(v & 0xffffu));
    a1 += w * bf2f((unsigned short)(v >> 16));
  }
  atomicAdd(&rf[r * H + tid * 2], a0);
  atomicAdd(&rf[r * H + tid * 2 + 1], a1);
}

// ---------------- K4ab: se = GELU(rf @ Ws + bs); ss = tanh(se@Wsa1+bsa1).Wsa2+bsa2 ----------------
__global__ __launch_bounds__(256) void k4ab(const float* __restrict__ rf,
                                            const float* __restrict__ Ws,
                                            const float* __restrict__ bs,
                                            const float* __restrict__ Wsa1,
                                            const float* __restrict__ bsa1,
                                            const float* __restrict__ Wsa2,
                                            const float* __restrict__ bsa2,
                                            float* __restrict__ se,
                                            float* __restrict__ ss) {
  const int r = blockIdx.x, tid = threadIdx.x;
  __shared__ float lrf[H];
  __shared__ float lse[H];
  __shared__ float red[256];
  lrf[tid] = rf[r * H + tid];
  lrf[tid + 256] = rf[r * H + tid + 256];
  __syncthreads();
  float a0 = 0.0f, a1 = 0.0f;
  for (int k = 0; k < H; k++) {
    float x = lrf[k];
    a0 += x * Ws[k * H + tid];
    a1 += x * Ws[k * H + tid + 256];
  }
  float s0 = gelu_exact(a0 + bs[tid]);
  float s1 = gelu_exact(a1 + bs[tid + 256]);
  se[r * H + tid] = s0;
  se[r * H + tid + 256] = s1;
  lse[tid] = s0;
  lse[tid + 256] = s1;
  __syncthreads();
  float a = 0.0f;
  for (int k = 0; k < H; k++) a += lse[k] * Wsa1[k * HH + tid];
  red[tid] = tanhf(a + bsa1[tid]) * Wsa2[tid];
  __syncthreads();
  for (int s = 128; s > 0; s >>= 1) {
    if (tid < s) red[tid] += red[tid + s];
    __syncthreads();
  }
  if (tid == 0) ss[r] = red[0] + bsa2[0];
}

// ---------------- K4c: softmax over regions + classifier ----------------
__global__ __launch_bounds__(256) void k4c_final(const float* __restrict__ se,
                                                 const float* __restrict__ ss,
                                                 const float* __restrict__ Wc1,
                                                 const float* __restrict__ bc1,
                                                 const float* __restrict__ Wc2,
                                                 const float* __restrict__ bc2,
                                                 float* __restrict__ out) {
  const int tid = threadIdx.x;
  __shared__ float srep[H];
  __shared__ float r0[256], r1[256];
  float mx = -1e30f;
  for (int i = 0; i < NREG; i++) mx = fmaxf(mx, ss[i]);
  float wv[NREG];
  float den = 0.0f;
  for (int i = 0; i < NREG; i++) { wv[i] = expf(ss[i] - mx); den += wv[i]; }
  float inv = 1.0f / den;
  float s0 = 0.0f, s1 = 0.0f;
  for (int i = 0; i < NREG; i++) {
    float w = wv[i] * inv;
    s0 += w * se[i * H + tid];
    s1 += w * se[i * H + tid + 256];
  }
  srep[tid] = s0;
  srep[tid + 256] = s1;
  __syncthreads();
  float a = 0.0f;
  for (int k = 0; k < H; k++) a += srep[k] * Wc1[k * HH + tid];
  float g = gelu_exact(a + bc1[tid]);
  r0[tid] = g * Wc2[tid * 2];
  r1[tid] = g * Wc2[tid * 2 + 1];
  __syncthreads();
  for (int s = 128; s > 0; s >>= 1) {
    if (tid < s) { r0[tid] += r0[tid + s]; r1[tid] += r1[tid + s]; }
    __syncthreads();
  }
  if (tid == 0) {
    out[0] = r0[0] + bc2[0];
    out[1] = r1[0] + bc2[1];
  }
}

// ---------------- launcher ----------------
extern "C" void kernel_launch(void* const* d_in, const int* in_sizes, int n_in,
                              void* d_out, int out_size, void* d_ws, size_t ws_size,
                              hipStream_t stream) {
  const float* X    = (const float*)d_in[0];
  const float* W1   = (const float*)d_in[1];
  const float* b1   = (const float*)d_in[2];
  const float* Wa1  = (const float*)d_in[3];
  const float* ba1  = (const float*)d_in[4];
  const float* Wa2  = (const float*)d_in[5];
  // d_in[6] = ba2: constant shift inside softmax -> no effect, unused
  const float* Ws   = (const float*)d_in[7];
  const float* bs   = (const float*)d_in[8];
  const float* Wsa1 = (const float*)d_in[9];
  const float* bsa1 = (const float*)d_in[10];
  const float* Wsa2 = (const float*)d_in[11];
  const float* bsa2 = (const float*)d_in[12];
  const float* Wc1  = (const float*)d_in[13];
  const float* bc1  = (const float*)d_in[14];
  const float* Wc2  = (const float*)d_in[15];
  const float* bc2  = (const float*)d_in[16];
  float* out = (float*)d_out;

  char* ws = (char*)d_ws;
  constexpr size_t OFF_W1T  = 0;                                    // 1 MiB
  constexpr size_t OFF_WA1T = OFF_W1T + (size_t)H * DIN * 2;        // +256 KiB
  constexpr size_t OFF_EB   = OFF_WA1T + (size_t)HH * H * 2;        // +64 MiB
  constexpr size_t OFF_SC   = OFF_EB + (size_t)NTOK * H * 2;        // scores 256 KiB (region-major)
  constexpr size_t OFF_RF   = OFF_SC + (size_t)NTOK * 4;            // rf 32 KiB
  constexpr size_t OFF_WT   = OFF_RF + (size_t)NREG * H * 4;        // wts 256 KiB (region-major)
  constexpr size_t OFF_SE   = OFF_WT + (size_t)NTOK * 4;            // se 32 KiB
  constexpr size_t OFF_SS   = OFF_SE + (size_t)NREG * H * 4;        // ss 64 B

  unsigned short* W1t  = (unsigned short*)(ws + OFF_W1T);
  unsigned short* Wa1t = (unsigned short*)(ws + OFF_WA1T);
  unsigned short* Eb   = (unsigned short*)(ws + OFF_EB);
  float* scores = (float*)(ws + OFF_SC);
  float* rf     = (float*)(ws + OFF_RF);
  float* wts    = (float*)(ws + OFF_WT);
  float* se     = (float*)(ws + OFF_SE);
  float* ssb    = (float*)(ws + OFF_SS);

  hipMemsetAsync(rf, 0, (size_t)NREG * H * 4, stream);

  k0_prep<<<(DIN * H + HH * H) / 256, 256, 0, stream>>>(W1, Wa1, W1t, Wa1t);
  k12_fused<<<512, 512, 0, stream>>>(X, W1t, b1, Wa1t, ba1, Wa2, Eb, scores);
  k3a_softmax<<<NREG, 256, 0, stream>>>(scores, wts);
  k3b_wsum<<<dim3(32, NREG), 256, 0, stream>>>(Eb, wts, rf);
  k4ab<<<NREG, 256, 0, stream>>>(rf, Ws, bs, Wsa1, bsa1, Wsa2, bsa2, se, ssb);
  k4c_final<<<1, 256, 0, stream>>>(se, ssb, Wc1, bc1, Wc2, bc2, out);
}